// Round 1
// baseline (248.470 us; speedup 1.0000x reference)
//
#include <hip/hip_runtime.h>

#define BATCH 4096
#define TLEN 750
#define WIN 11

// Block-wide sum reduction. Returns the full sum on thread 0 only.
// Deterministic: fixed shuffle tree + fixed 4-term add.
__device__ __forceinline__ float block_reduce_sum(float v, float* red) {
    #pragma unroll
    for (int off = 32; off > 0; off >>= 1) v += __shfl_down(v, off, 64);
    const int t = threadIdx.x;
    if ((t & 63) == 0) red[t >> 6] = v;
    __syncthreads();
    float r = 0.f;
    if (t == 0) r = (red[0] + red[1]) + (red[2] + red[3]);
    __syncthreads();   // protect red[] before next call reuses it
    return r;
}

// One block per output column i. Threads stride over the batch dimension.
__global__ __launch_bounds__(256) void actloss_col_kernel(
        const float* __restrict__ a,    // actioness   [BATCH][TLEN]
        const float* __restrict__ a2,   // actioness_2 [BATCH][TLEN]
        float* __restrict__ part) {     // [TLEN] per-column partial loss
    const int i = blockIdx.x;
    const int t = threadIdx.x;
    __shared__ float red[4];

    // window column indices, clamp(i + j - 6, 0, TLEN-1); uniform per block
    int cidx[WIN];
    #pragma unroll
    for (int j = 0; j < WIN; ++j) {
        int c = i + j - 6;
        cidx[j] = c < 0 ? 0 : (c > TLEN - 1 ? TLEN - 1 : c);
    }

    float s1[WIN], s2[WIN];
    #pragma unroll
    for (int j = 0; j < WIN; ++j) { s1[j] = 0.f; s2[j] = 0.f; }
    float resacc = 0.f;

    for (int b = t; b < BATCH; b += 256) {
        const float* arow  = a  + (size_t)b * TLEN;
        const float* a2row = a2 + (size_t)b * TLEN;
        const float ai  = arow[i];
        const float a2i = a2row[i];
        const float r = ai - a2i;
        resacc = fmaf(r, r, resacc);
        #pragma unroll
        for (int j = 0; j < WIN; ++j) {
            const float d = ai - arow[cidx[j]];
            s1[j] = fmaf(d, d, s1[j]);
            s2[j] += fabsf(a2i - a2row[cidx[j]]);
        }
    }

    // reduce the 23 accumulators across the block
    float term = 0.f;
    #pragma unroll
    for (int j = 0; j < WIN; ++j) {
        const float s1r = block_reduce_sum(s1[j], red);
        const float s2r = block_reduce_sum(s2[j], red);
        if (t == 0) term += expf(-0.5f * s1r) * s2r;   // w[i,j] * sum_b|.|
    }
    const float resr = block_reduce_sum(resacc, red);

    if (t == 0) {
        const float inv_b = 1.0f / (float)BATCH;
        // term1 contribution (mean over batch) + E_THETA * mean_b res^2 slice
        part[i] = term * inv_b + 0.1f * inv_b * resr;
    }
}

// Deterministic final reduction of 750 partials -> scalar.
__global__ __launch_bounds__(256) void actloss_reduce_kernel(
        const float* __restrict__ part, float* __restrict__ out) {
    __shared__ float red[4];
    float v = 0.f;
    for (int k = threadIdx.x; k < TLEN; k += 256) v += part[k];
    const float r = block_reduce_sum(v, red);
    if (threadIdx.x == 0) out[0] = r;   // E_ALPHA = 1.0
}

extern "C" void kernel_launch(void* const* d_in, const int* in_sizes, int n_in,
                              void* d_out, int out_size, void* d_ws, size_t ws_size,
                              hipStream_t stream) {
    const float* a  = (const float*)d_in[0];   // actioness
    const float* a2 = (const float*)d_in[1];   // actioness_2
    float* out  = (float*)d_out;
    float* part = (float*)d_ws;                // 750 floats = 3 KB scratch

    actloss_col_kernel<<<TLEN, 256, 0, stream>>>(a, a2, part);
    actloss_reduce_kernel<<<1, 256, 0, stream>>>(part, out);
}

// Round 2
// 50.868 us; speedup vs baseline: 4.8846x; 4.8846x over previous
//
#include <hip/hip_runtime.h>

#define BATCH 4096
#define TLEN  750
#define WIN   11
#define SEG   760      // 6 left halo + 750 + 4 right halo (max index needed: 749+10=759)
#define P1    8256     // pitch of per-group (i,j) partial row (750*11=8250, padded)
#define PR    768      // pitch of per-group res partial row

// ---------------- shared helpers ----------------

__device__ __forceinline__ float block_reduce_sum(float v, float* red) {
    #pragma unroll
    for (int off = 32; off > 0; off >>= 1) v += __shfl_down(v, off, 64);
    const int t = threadIdx.x;
    if ((t & 63) == 0) red[t >> 6] = v;
    __syncthreads();
    float r = 0.f;
    if (t == 0) r = (red[0] + red[1]) + (red[2] + red[3]);
    __syncthreads();
    return r;
}

// ---------------- fast path ----------------

// K1: one block per row-group. Threads = columns (coalesced). Double-buffered
// LDS row staging with register prefetch. Each thread owns column i = tid and
// accumulates s1[11], s2[11], res over its R rows in registers.
__global__ __launch_bounds__(768) void actloss_k1(
        const float* __restrict__ a, const float* __restrict__ a2,
        float* __restrict__ s1p, float* __restrict__ s2p,
        float* __restrict__ resp, int R) {
    __shared__ float sA[2][768], sA2[2][768];
    const int t = threadIdx.x;
    const int g = blockIdx.x;
    const int b0 = g * R;
    const int src = min(max(t - 6, 0), TLEN - 1);   // clamped column this thread stages

    float s1[WIN], s2[WIN];
    #pragma unroll
    for (int j = 0; j < WIN; ++j) { s1[j] = 0.f; s2[j] = 0.f; }
    float resacc = 0.f;

    // prologue: stage row b0 into buffer 0
    float pa = 0.f, pa2 = 0.f;
    if (t < SEG) {
        pa  = a [(size_t)b0 * TLEN + src];
        pa2 = a2[(size_t)b0 * TLEN + src];
        sA[0][t] = pa; sA2[0][t] = pa2;
    }
    __syncthreads();

    int cur = 0;
    for (int r = 0; r < R; ++r) {
        // prefetch next row into registers (latency hides under compute)
        if (r + 1 < R && t < SEG) {
            pa  = a [(size_t)(b0 + r + 1) * TLEN + src];
            pa2 = a2[(size_t)(b0 + r + 1) * TLEN + src];
        }
        if (t < TLEN) {
            const float ai  = sA [cur][t + 6];
            const float a2i = sA2[cur][t + 6];
            const float rr = ai - a2i;
            resacc = fmaf(rr, rr, resacc);
            #pragma unroll
            for (int j = 0; j < WIN; ++j) {
                const float d = ai - sA[cur][t + j];     // window col clamp(i+j-6)
                s1[j] = fmaf(d, d, s1[j]);
                s2[j] += fabsf(a2i - sA2[cur][t + j]);
            }
        }
        if (r + 1 < R) {
            // write prefetched row into the OTHER buffer: no WAR with readers of cur
            if (t < SEG) { sA[cur ^ 1][t] = pa; sA2[cur ^ 1][t] = pa2; }
            __syncthreads();
            cur ^= 1;
        }
    }

    if (t < TLEN) {
        const size_t base = (size_t)g * P1 + (size_t)t * WIN;
        #pragma unroll
        for (int j = 0; j < WIN; ++j) { s1p[base + j] = s1[j]; s2p[base + j] = s2[j]; }
        resp[(size_t)g * PR + t] = resacc;
    }
}

// K2: one block per column i. Reduce over the G row-groups, apply exp, res term.
__global__ __launch_bounds__(256) void actloss_k2(
        const float* __restrict__ s1p, const float* __restrict__ s2p,
        const float* __restrict__ resp, float* __restrict__ part, int G) {
    const int i = blockIdx.x;
    const int t = threadIdx.x;
    const int w = t >> 6, l = t & 63;
    __shared__ float wterm[WIN];
    __shared__ float red[4];

    // res partial for this column
    float rr = 0.f;
    for (int gg = t; gg < G; gg += 256) rr += resp[(size_t)gg * PR + i];
    const float res_i = block_reduce_sum(rr, red);   // valid on thread 0

    // wave w handles j = w, w+4, w+8
    for (int j = w; j < WIN; j += 4) {
        float s1 = 0.f, s2 = 0.f;
        for (int gg = l; gg < G; gg += 64) {
            const size_t o = (size_t)gg * P1 + (size_t)i * WIN + j;
            s1 += s1p[o]; s2 += s2p[o];
        }
        #pragma unroll
        for (int off = 32; off > 0; off >>= 1) {
            s1 += __shfl_down(s1, off, 64);
            s2 += __shfl_down(s2, off, 64);
        }
        if (l == 0) wterm[j] = expf(-0.5f * s1) * s2;
    }
    __syncthreads();

    if (t == 0) {
        float term = 0.f;
        #pragma unroll
        for (int j = 0; j < WIN; ++j) term += wterm[j];
        part[i] = (term + 0.1f * res_i) * (1.0f / (float)BATCH);
    }
}

// K3: deterministic 750 -> scalar
__global__ __launch_bounds__(256) void actloss_k3(
        const float* __restrict__ part, float* __restrict__ out) {
    __shared__ float red[4];
    float v = 0.f;
    for (int k = threadIdx.x; k < TLEN; k += 256) v += part[k];
    const float r = block_reduce_sum(v, red);
    if (threadIdx.x == 0) out[0] = r;   // E_ALPHA = 1.0
}

// ---------------- fallback slow path (round-1 kernel, known-good) ----------------

__global__ __launch_bounds__(256) void actloss_col_kernel(
        const float* __restrict__ a, const float* __restrict__ a2,
        float* __restrict__ part) {
    const int i = blockIdx.x;
    const int t = threadIdx.x;
    __shared__ float red[4];
    int cidx[WIN];
    #pragma unroll
    for (int j = 0; j < WIN; ++j) {
        int c = i + j - 6;
        cidx[j] = c < 0 ? 0 : (c > TLEN - 1 ? TLEN - 1 : c);
    }
    float s1[WIN], s2[WIN];
    #pragma unroll
    for (int j = 0; j < WIN; ++j) { s1[j] = 0.f; s2[j] = 0.f; }
    float resacc = 0.f;
    for (int b = t; b < BATCH; b += 256) {
        const float* arow  = a  + (size_t)b * TLEN;
        const float* a2row = a2 + (size_t)b * TLEN;
        const float ai = arow[i], a2i = a2row[i];
        const float r = ai - a2i;
        resacc = fmaf(r, r, resacc);
        #pragma unroll
        for (int j = 0; j < WIN; ++j) {
            const float d = ai - arow[cidx[j]];
            s1[j] = fmaf(d, d, s1[j]);
            s2[j] += fabsf(a2i - a2row[cidx[j]]);
        }
    }
    float term = 0.f;
    #pragma unroll
    for (int j = 0; j < WIN; ++j) {
        const float s1r = block_reduce_sum(s1[j], red);
        const float s2r = block_reduce_sum(s2[j], red);
        if (t == 0) term += expf(-0.5f * s1r) * s2r;
    }
    const float resr = block_reduce_sum(resacc, red);
    if (t == 0) part[i] = (term + 0.1f * resr) * (1.0f / (float)BATCH);
}

// ---------------- launcher ----------------

extern "C" void kernel_launch(void* const* d_in, const int* in_sizes, int n_in,
                              void* d_out, int out_size, void* d_ws, size_t ws_size,
                              hipStream_t stream) {
    const float* a  = (const float*)d_in[0];   // actioness
    const float* a2 = (const float*)d_in[1];   // actioness_2
    float* out = (float*)d_out;
    float* ws  = (float*)d_ws;

    // pick largest group count that fits in ws (deterministic for fixed ws_size)
    int G = 0;
    for (int cand = 256; cand >= 8; cand >>= 1) {
        const size_t need = ((size_t)2 * cand * P1 + (size_t)cand * PR + TLEN + 16) * 4;
        if (need <= ws_size) { G = cand; break; }
    }

    if (G == 0) {
        // tiny ws: known-good slow path (needs 750 floats)
        float* part = ws;
        actloss_col_kernel<<<TLEN, 256, 0, stream>>>(a, a2, part);
        actloss_k3<<<1, 256, 0, stream>>>(part, out);
        return;
    }

    float* s1p  = ws;
    float* s2p  = s1p + (size_t)G * P1;
    float* resp = s2p + (size_t)G * P1;
    float* part = resp + (size_t)G * PR;
    const int R = BATCH / G;

    actloss_k1<<<G, 768, 0, stream>>>(a, a2, s1p, s2p, resp, R);
    actloss_k2<<<TLEN, 256, 0, stream>>>(s1p, s2p, resp, part, G);
    actloss_k3<<<1, 256, 0, stream>>>(part, out);
}

// Round 3
// 48.751 us; speedup vs baseline: 5.0968x; 1.0434x over previous
//
#include <hip/hip_runtime.h>

#define BATCH 4096
#define TLEN  750
#define NK    6            // pair offsets k = 1..6 (k=0 contributes exactly 0)
#define CPT   4            // columns per thread
#define NTH1  192          // K1 block size (3 waves; threads 0..187 own columns)
#define NCG   188          // active col-group threads: ceil(750/4)
#define GGRP  512          // row groups
#define RPG   (BATCH/GGRP) // 8 rows per group (even, so row parity is compile-time)
#define PSTR  752          // i-stride inside partials (16B-aligned blocks)
#define HALF  (NK*PSTR)    // 4512 floats: all s1 slots (s2 at +HALF)
#define PSZ   (2*HALF)     // 9024 floats per group
#define NCH   16           // reduction chunks over groups
#define GPC   (GGRP/NCH)   // 32 groups per chunk
#define NSB   36           // slot-blocks per chunk in K2a: 36*256 >= 9024

// ---------------- helpers ----------------

template<int NW>
__device__ __forceinline__ float block_reduce(float v, float* red) {
    #pragma unroll
    for (int off = 32; off > 0; off >>= 1) v += __shfl_down(v, off, 64);
    const int t = threadIdx.x;
    if ((t & 63) == 0) red[t >> 6] = v;
    __syncthreads();
    float r = 0.f;
    if (t == 0) {
        #pragma unroll
        for (int w = 0; w < NW; ++w) r += red[w];
    }
    __syncthreads();
    return r;
}

// Even row: (row base) % 4 floats == 0; starts s = i0+4u are 16B-aligned.
// Loads window cols [i0 .. i0+11] into w[0..11]; edge threads load less
// (never past column 749 of the row -> never out of buffer).
__device__ __forceinline__ void load3e(const float* __restrict__ row, int i0, float* w) {
    #pragma unroll
    for (int u = 0; u < 3; ++u) {
        const int s = i0 + 4 * u;
        if (s + 3 <= TLEN - 1) {
            const float4 v = *reinterpret_cast<const float4*>(row + s);
            w[4*u+0] = v.x; w[4*u+1] = v.y; w[4*u+2] = v.z; w[4*u+3] = v.w;
        } else if (s == TLEN - 2) {   // s == 748: 8B-aligned pair {748,749}
            const float2 v = *reinterpret_cast<const float2*>(row + s);
            w[4*u+0] = v.x; w[4*u+1] = v.y;
        }
    }
}

// Odd row: (row base) % 4 floats == 2; starts s = i0-2+4u ( == 2 mod 4) are
// 16B-aligned against the odd base. Window cols [i0-2 .. i0+9] -> col i0+m
// lives at w[m+2]. s = -2 (t==0) reads the previous row's tail: in-bounds
// (odd rows >= 1) and those regs are never used by compute.
__device__ __forceinline__ void load3o(const float* __restrict__ row, int i0, float* w) {
    #pragma unroll
    for (int u = 0; u < 3; ++u) {
        const int s = i0 - 2 + 4 * u;
        if (s + 3 <= TLEN - 1) {
            const float4 v = *reinterpret_cast<const float4*>(row + s);
            w[4*u+0] = v.x; w[4*u+1] = v.y; w[4*u+2] = v.z; w[4*u+3] = v.w;
        }
    }
}

// ---------------- K1: per-group pair partials, no LDS ----------------
// Thread t owns columns i0..i0+3. For k=1..6 accumulates over its R rows:
//   s1[c][k-1] += (a[b,i]-a[b,i+k])^2 ;  s2[c][k-1] += |a2[b,i]-a2[b,i+k]|
// plus res += (a[b,i]-a2[b,i])^2. Pairs with i+k>749 accumulate garbage but
// are finite (zero-init regs) and provably never read downstream.
__global__ __launch_bounds__(NTH1) void actloss_k1(
        const float* __restrict__ a, const float* __restrict__ a2,
        float* __restrict__ p, float* __restrict__ resp) {
    const int t  = threadIdx.x;
    const int g  = blockIdx.x;
    const int i0 = t * CPT;
    const int b0 = g * RPG;

    float s1[CPT][NK], s2[CPT][NK];
    #pragma unroll
    for (int c = 0; c < CPT; ++c)
        #pragma unroll
        for (int k = 0; k < NK; ++k) { s1[c][k] = 0.f; s2[c][k] = 0.f; }
    float res = 0.f;

    float wea[12] = {}, web[12] = {}, woa[12] = {}, wob[12] = {};

    #pragma unroll
    for (int rp = 0; rp < RPG / 2; ++rp) {
        const float* ra = a  + (size_t)(b0 + 2 * rp) * TLEN;
        const float* rb = a2 + (size_t)(b0 + 2 * rp) * TLEN;
        load3e(ra, i0, wea);        load3e(rb, i0, web);
        load3o(ra + TLEN, i0, woa); load3o(rb + TLEN, i0, wob);

        // even row (shift 0)
        #pragma unroll
        for (int c = 0; c < CPT; ++c) {
            const float av = wea[c], bv = web[c];
            #pragma unroll
            for (int k = 1; k <= NK; ++k) {
                const float d = av - wea[c + k];
                s1[c][k-1] = fmaf(d, d, s1[c][k-1]);
                s2[c][k-1] += fabsf(bv - web[c + k]);
            }
            if (i0 + c < TLEN) { const float rr = av - bv; res = fmaf(rr, rr, res); }
        }
        // odd row (shift 2)
        #pragma unroll
        for (int c = 0; c < CPT; ++c) {
            const float av = woa[c + 2], bv = wob[c + 2];
            #pragma unroll
            for (int k = 1; k <= NK; ++k) {
                const float d = av - woa[c + 2 + k];
                s1[c][k-1] = fmaf(d, d, s1[c][k-1]);
                s2[c][k-1] += fabsf(bv - wob[c + 2 + k]);
            }
            if (i0 + c < TLEN) { const float rr = av - bv; res = fmaf(rr, rr, res); }
        }
    }

    // store partials: [g][ (k-1)*PSTR + i ] (s1), +HALF (s2), float4-coalesced
    if (t < NCG) {
        float* pg = p + (size_t)g * PSZ;
        #pragma unroll
        for (int k = 0; k < NK; ++k) {
            *reinterpret_cast<float4*>(pg + (size_t)k * PSTR + i0) =
                make_float4(s1[0][k], s1[1][k], s1[2][k], s1[3][k]);
            *reinterpret_cast<float4*>(pg + HALF + (size_t)k * PSTR + i0) =
                make_float4(s2[0][k], s2[1][k], s2[2][k], s2[3][k]);
        }
    }

    __shared__ float red[3];
    const float rsum = block_reduce<3>(res, red);
    if (t == 0) resp[g] = rsum;
}

// ---------------- K2a: reduce groups within a chunk (coalesced) ----------------
__global__ __launch_bounds__(256) void actloss_k2a(
        const float* __restrict__ p, float* __restrict__ out2) {
    const int sb = blockIdx.x % NSB;
    const int ch = blockIdx.x / NSB;
    const int slot = sb * 256 + threadIdx.x;
    if (slot >= PSZ) return;
    const float* base = p + (size_t)ch * GPC * PSZ + slot;
    float s = 0.f;
    #pragma unroll 8
    for (int q = 0; q < GPC; ++q) s += base[(size_t)q * PSZ];
    out2[(size_t)ch * PSZ + slot] = s;
}

// ---------------- K2b: reduce chunks, apply exp -> per-pair term ----------------
__global__ __launch_bounds__(256) void actloss_k2b(
        const float* __restrict__ out2, float* __restrict__ T) {
    const int slot = blockIdx.x * 256 + threadIdx.x;
    if (slot >= HALF) return;
    float v1 = 0.f, v2 = 0.f;
    #pragma unroll
    for (int ch = 0; ch < NCH; ++ch) {
        v1 += out2[(size_t)ch * PSZ + slot];
        v2 += out2[(size_t)ch * PSZ + HALF + slot];
    }
    T[slot] = expf(-0.5f * v1) * v2;
}

// ---------------- K3: map 8250 (i,j) terms onto pairs + res term ----------------
__global__ __launch_bounds__(256) void actloss_k3(
        const float* __restrict__ T, const float* __restrict__ resp,
        float* __restrict__ out) {
    __shared__ float red[4];
    const int t = threadIdx.x;
    float acc = 0.f;
    for (int idx = t; idx < TLEN * 11; idx += 256) {
        const int i = idx / 11, j = idx - i * 11;
        int c = i + j - 6;
        c = c < 0 ? 0 : (c > TLEN - 1 ? TLEN - 1 : c);
        const int k = abs(i - c);
        if (k > 0) {
            const int lo = i < c ? i : c;
            acc += T[(k - 1) * PSTR + lo];
        }
    }
    float racc = 0.f;
    for (int q = t; q < GGRP; q += 256) racc += resp[q];

    const float accR  = block_reduce<4>(acc, red);
    const float raccR = block_reduce<4>(racc, red);
    if (t == 0) out[0] = (accR + 0.1f * raccR) * (1.0f / (float)BATCH);
}

// ---------------- fallback slow path (round-1, known-good) ----------------

__global__ __launch_bounds__(256) void actloss_col_kernel(
        const float* __restrict__ a, const float* __restrict__ a2,
        float* __restrict__ part) {
    const int i = blockIdx.x;
    const int t = threadIdx.x;
    __shared__ float red[4];
    int cidx[11];
    #pragma unroll
    for (int j = 0; j < 11; ++j) {
        int c = i + j - 6;
        cidx[j] = c < 0 ? 0 : (c > TLEN - 1 ? TLEN - 1 : c);
    }
    float s1[11], s2[11];
    #pragma unroll
    for (int j = 0; j < 11; ++j) { s1[j] = 0.f; s2[j] = 0.f; }
    float resacc = 0.f;
    for (int b = t; b < BATCH; b += 256) {
        const float* arow  = a  + (size_t)b * TLEN;
        const float* a2row = a2 + (size_t)b * TLEN;
        const float ai = arow[i], a2i = a2row[i];
        const float r = ai - a2i;
        resacc = fmaf(r, r, resacc);
        #pragma unroll
        for (int j = 0; j < 11; ++j) {
            const float d = ai - arow[cidx[j]];
            s1[j] = fmaf(d, d, s1[j]);
            s2[j] += fabsf(a2i - a2row[cidx[j]]);
        }
    }
    float term = 0.f;
    #pragma unroll
    for (int j = 0; j < 11; ++j) {
        const float s1r = block_reduce<4>(s1[j], red);
        const float s2r = block_reduce<4>(s2[j], red);
        if (t == 0) term += expf(-0.5f * s1r) * s2r;
    }
    const float resr = block_reduce<4>(resacc, red);
    if (t == 0) part[i] = (term + 0.1f * resr) * (1.0f / (float)BATCH);
}

__global__ __launch_bounds__(256) void actloss_fallback_reduce(
        const float* __restrict__ part, float* __restrict__ out) {
    __shared__ float red[4];
    float v = 0.f;
    for (int k = threadIdx.x; k < TLEN; k += 256) v += part[k];
    const float r = block_reduce<4>(v, red);
    if (threadIdx.x == 0) out[0] = r;
}

// ---------------- launcher ----------------

extern "C" void kernel_launch(void* const* d_in, const int* in_sizes, int n_in,
                              void* d_out, int out_size, void* d_ws, size_t ws_size,
                              hipStream_t stream) {
    const float* a  = (const float*)d_in[0];   // actioness
    const float* a2 = (const float*)d_in[1];   // actioness_2
    float* out = (float*)d_out;
    float* ws  = (float*)d_ws;

    const size_t need = ((size_t)GGRP * PSZ + (size_t)NCH * PSZ + HALF + GGRP + 64)
                        * sizeof(float);
    if (ws_size >= need) {
        float* p    = ws;
        float* out2 = p + (size_t)GGRP * PSZ;
        float* T    = out2 + (size_t)NCH * PSZ;
        float* resp = T + HALF;
        actloss_k1 <<<GGRP, NTH1, 0, stream>>>(a, a2, p, resp);
        actloss_k2a<<<NCH * NSB, 256, 0, stream>>>(p, out2);
        actloss_k2b<<<(HALF + 255) / 256, 256, 0, stream>>>(out2, T);
        actloss_k3 <<<1, 256, 0, stream>>>(T, resp, out);
    } else {
        float* part = ws;   // 750 floats
        actloss_col_kernel<<<TLEN, 256, 0, stream>>>(a, a2, part);
        actloss_fallback_reduce<<<1, 256, 0, stream>>>(part, out);
    }
}